// Round 3
// baseline (81.293 us; speedup 1.0000x reference)
//
#include <hip/hip_runtime.h>

#define DIM    64      // CELL_DIM
#define NCELLS 512
#define CC     256     // cells per cell-chunk (2 chunks)
#define KC     32      // k-rows per k-chunk  (2 chunks)
#define ROWS_PER_BLOCK 8
#define NROWS  8192

// Block: 256 thr = 4 waves; wave w owns rows blk*8 + 2w + {0,1}.
// Lane l owns cells {4l..4l+3} (cc=0) and {256+4l..+3} (cc=1).
// pc staged in 4 stages of 32 KB (KC x CC, [k][cell] transposed, XOR-swizzled:
// phys_quad = logical_quad ^ k4) -> conflict-free ds_read_b128, 2-way (free)
// scatter writes. 32 KB LDS -> 4 blocks/CU (vs 2 at R2's 64 KB): barrier
// drains and ds_read latency now hide across blocks.
// Accumulators are named float4s — R1 showed indexed local arrays spill to
// scratch (800 MB HBM round-trip).
__global__ __launch_bounds__(256, 4)
void placecells_kernel(const float* __restrict__ x,
                       const float* __restrict__ pc,
                       float* __restrict__ out)
{
    __shared__ float pcT[KC * CC];   // 32 KB

    const int tid = (int)threadIdx.x;
    const int l   = tid & 63;
    // wave id via readfirstlane -> provably uniform x addressing (s_load path)
    const int w   = __builtin_amdgcn_readfirstlane(tid >> 6);
    const int rowBase = (int)blockIdx.x * ROWS_PER_BLOCK + w * 2;

    float4 a00{0,0,0,0}, a10{0,0,0,0};   // rows 0/1, cell-chunk 0
    float4 a01{0,0,0,0}, a11{0,0,0,0};   // rows 0/1, cell-chunk 1

    auto stage = [&](int cc, int kc) {
        #pragma unroll
        for (int i = 0; i < 8; ++i) {
            int idx = i * 256 + tid;
            int cl  = idx >> 3;          // cell in chunk, 0..255
            int k4  = idx & 7;           // k-quad in chunk, 0..7 (coalesced)
            float4 v = *(const float4*)(pc + (cc * CC + cl) * DIM + kc * KC + k4 * 4);
            int pq = (cl >> 2) ^ k4;     // bank swizzle
            float* p = &pcT[(k4 * 4) * CC + pq * 4 + (cl & 3)];
            p[0 * CC] = v.x;
            p[1 * CC] = v.y;
            p[2 * CC] = v.z;
            p[3 * CC] = v.w;
        }
    };

    auto compute = [&](int kc, float4& A0, float4& A1) {
        #pragma unroll
        for (int k4 = 0; k4 < 8; ++k4) {
            float4 xv0 = *(const float4*)(x + (rowBase + 0) * DIM + kc * KC + k4 * 4);
            float4 xv1 = *(const float4*)(x + (rowBase + 1) * DIM + kc * KC + k4 * 4);
            const int pq4 = (l ^ k4) * 4;   // undo swizzle: logical quad = l
            #pragma unroll
            for (int j = 0; j < 4; ++j) {
                float4 pv = *(const float4*)(&pcT[(k4 * 4 + j) * CC + pq4]);
                float x0 = (j == 0) ? xv0.x : (j == 1) ? xv0.y : (j == 2) ? xv0.z : xv0.w;
                float x1 = (j == 0) ? xv1.x : (j == 1) ? xv1.y : (j == 2) ? xv1.z : xv1.w;
                A0.x += fabsf(x0 - pv.x); A0.y += fabsf(x0 - pv.y);
                A0.z += fabsf(x0 - pv.z); A0.w += fabsf(x0 - pv.w);
                A1.x += fabsf(x1 - pv.x); A1.y += fabsf(x1 - pv.y);
                A1.z += fabsf(x1 - pv.z); A1.w += fabsf(x1 - pv.w);
            }
        }
    };

    stage(0, 0); __syncthreads();
    compute(0, a00, a10);
    __syncthreads(); stage(0, 1); __syncthreads();
    compute(1, a00, a10);
    __syncthreads(); stage(1, 0); __syncthreads();
    compute(0, a01, a11);
    __syncthreads(); stage(1, 1); __syncthreads();
    compute(1, a01, a11);

    // ---- softmax per row over 512 cells (one wave holds a whole row) ----
    auto finish_row = [&](float4 a, float4 b, int r) {
        // min L1 == min d^2 (d >= 0) -> exact max-subtraction, no underflow
        float mn = fminf(fminf(fminf(a.x, a.y), fminf(a.z, a.w)),
                         fminf(fminf(b.x, b.y), fminf(b.z, b.w)));
        #pragma unroll
        for (int off = 32; off > 0; off >>= 1)
            mn = fminf(mn, __shfl_xor(mn, off, 64));
        float m2 = mn * mn;

        float e0 = __expf(0.5f * (m2 - a.x * a.x));
        float e1 = __expf(0.5f * (m2 - a.y * a.y));
        float e2 = __expf(0.5f * (m2 - a.z * a.z));
        float e3 = __expf(0.5f * (m2 - a.w * a.w));
        float e4 = __expf(0.5f * (m2 - b.x * b.x));
        float e5 = __expf(0.5f * (m2 - b.y * b.y));
        float e6 = __expf(0.5f * (m2 - b.z * b.z));
        float e7 = __expf(0.5f * (m2 - b.w * b.w));
        float s = ((e0 + e1) + (e2 + e3)) + ((e4 + e5) + (e6 + e7));
        #pragma unroll
        for (int off = 32; off > 0; off >>= 1)
            s += __shfl_xor(s, off, 64);
        float inv = 1.0f / s;

        float* orow = out + (size_t)(rowBase + r) * NCELLS;
        *(float4*)(orow + 4 * l)      = make_float4(e0 * inv, e1 * inv, e2 * inv, e3 * inv);
        *(float4*)(orow + CC + 4 * l) = make_float4(e4 * inv, e5 * inv, e6 * inv, e7 * inv);
    };
    finish_row(a00, a01, 0);
    finish_row(a10, a11, 1);
}

extern "C" void kernel_launch(void* const* d_in, const int* in_sizes, int n_in,
                              void* d_out, int out_size, void* d_ws, size_t ws_size,
                              hipStream_t stream)
{
    const float* x  = (const float*)d_in[0];   // (8192, 64) fp32
    const float* pc = (const float*)d_in[1];   // (512, 64) fp32
    float* out = (float*)d_out;                // (8192, 512) fp32
    placecells_kernel<<<dim3(NROWS / ROWS_PER_BLOCK), dim3(256), 0, stream>>>(x, pc, out);
}